// Round 4
// baseline (20535.675 us; speedup 1.0000x reference)
//
#include <hip/hip_runtime.h>

// LSTM-with-projection (ELMo LSTMP), persistent-kernel, fp32-class precision.
// Round 4: kill the per-step L2 wbl2/inv (was 98% of runtime).
//  - Cross-block data (hpre, hbuf) via agent-scope relaxed atomics (sc1:
//    bypass incoherent L1/L2, served by memory-side Infinity Cache) -> the
//    grid barrier needs NO fences (syncthreads' vmcnt(0) drains sc1 stores).
//  - Read-only data (x, P, PT) via normal loads -> L1/L2 stay warm.
//  - One heavy fence (wbl2+inv) only at init to publish PT.
//  - Phase B: 64 consumer blocks x 8 cols (hpre broadcast 131->33 MB/step).
//  - Phase A unchanged: split-fp16 MFMA, weight fragments in registers.

#define NBLK 256
#define NTHR 256
#define B_   32
#define S_   128
#define D_   512
#define U_   4096
#define PJ   512
#define G4   16384
#define PITCH 1032    // xh row pitch (fp16 elems): 516 dwords -> bank rotation
#define LSCALE 2048.0f
#define LINV   4.8828125e-4f   // 1/2048
#define NCONS 64      // phase-B consumer blocks
#define CPB   8       // projection cols per consumer

typedef __attribute__((ext_vector_type(8))) _Float16 half8;
typedef __attribute__((ext_vector_type(4))) float floatx4;

__device__ __forceinline__ void split_h(float f, _Float16& hi, _Float16& lo) {
  _Float16 h = (_Float16)f;                  // RTNE
  hi = h;
  lo = (_Float16)((f - (float)h) * LSCALE);  // residual x2048: fp16-normal
}

// ---- device-coherent (agent-scope, sc1) data movement: no fences needed ----
__device__ __forceinline__ float2 ldg_dev8(const float* p) {
  unsigned long long v = __hip_atomic_load((const unsigned long long*)p,
                                           __ATOMIC_RELAXED,
                                           __HIP_MEMORY_SCOPE_AGENT);
  union { unsigned long long u; float2 f; } c; c.u = v; return c.f;
}
__device__ __forceinline__ void stg_dev4(float* p, float v) {
  __hip_atomic_store(p, v, __ATOMIC_RELAXED, __HIP_MEMORY_SCOPE_AGENT);
}

// light grid barrier: no cache maintenance. __syncthreads() lowers with
// s_waitcnt vmcnt(0) per wave -> all sc1 stores are device-visible before
// thread 0 signals the monotonic counter.
__device__ __forceinline__ void gsync(unsigned* bar) {
  __syncthreads();
  if (threadIdx.x == 0) {
    unsigned old = __hip_atomic_fetch_add(bar, 1u, __ATOMIC_RELAXED,
                                          __HIP_MEMORY_SCOPE_AGENT);
    unsigned target = (old / NBLK + 1u) * NBLK;
    while (__hip_atomic_load(bar, __ATOMIC_RELAXED,
                             __HIP_MEMORY_SCOPE_AGENT) < target)
      __builtin_amdgcn_s_sleep(1);
  }
  __syncthreads();
}

// heavy barrier (init only): publish normal-store data (PT) across XCDs
__device__ __forceinline__ void gsync_heavy(unsigned* bar) {
  __threadfence();              // release: waitcnt + wbl2
  __syncthreads();
  if (threadIdx.x == 0) {
    unsigned old = __hip_atomic_fetch_add(bar, 1u, __ATOMIC_RELAXED,
                                          __HIP_MEMORY_SCOPE_AGENT);
    unsigned target = (old / NBLK + 1u) * NBLK;
    while (__hip_atomic_load(bar, __ATOMIC_RELAXED,
                             __HIP_MEMORY_SCOPE_AGENT) < target)
      __builtin_amdgcn_s_sleep(1);
  }
  __syncthreads();
  __threadfence();              // acquire: inv stale L1/L2
}

__global__ __launch_bounds__(NTHR, 1)
void lstm_persistent(const float* __restrict__ x,
                     const float* __restrict__ Wk,
                     const float* __restrict__ R,
                     const float* __restrict__ bias,
                     const float* __restrict__ P,
                     float* __restrict__ out,
                     unsigned* __restrict__ bar,
                     float* __restrict__ hbuf,   // [32][512] f32 (zeroed)
                     float* __restrict__ hpre,   // [32][4096] f32
                     float* __restrict__ PT)     // [512][4096] f32 = P^T
{
  __shared__ __align__(16) _Float16 xh_hi[B_ * PITCH];  // 66048 B
  __shared__ __align__(16) _Float16 xh_lo[B_ * PITCH];  // 66048 B
  __shared__ __align__(16) float zb[2][64][36];         // 18432 B
  __shared__ float cst[512];                            //  2048 B
  __shared__ float biasL[64];

  const int tid  = threadIdx.x;
  const int blk  = blockIdx.x;
  const int lane = tid & 63;
  const int w    = tid >> 6;   // wave 0..3
  const int ch   = w & 1;      // col-half: 0 -> cols 0..31, 1 -> 32..63
  const int kh   = w >> 1;     // k-half:   0 -> x@Wk (k<512), 1 -> h@R

  // ---- one-time setup -------------------------------------------------
  if (tid < 64) {
    int g = tid >> 4, j = tid & 15;
    biasL[tid] = bias[g * U_ + blk * 16 + j];
  }
  cst[tid] = 0.f;
  cst[tid + 256] = 0.f;

  // transpose our 16 unit-rows of P into PT: PT[c][k] = P[k][c]
  for (int i = tid; i < 16 * PJ; i += NTHR) {
    int c  = i >> 4;
    int kr = i & 15;
    int k  = blk * 16 + kr;
    PT[(size_t)c * U_ + k] = P[(size_t)k * PJ + c];
  }

  // Weight B-fragments (split fp16) into registers.
  // B-frag (16x16x32): lane holds B[k=quad*8+j][n=lane&15].
  half8 bhi[2][16], blo[2][16];
  {
    const float* Wsrc = kh ? R : Wk;
    const int n = lane & 15, q = lane >> 4;
#pragma unroll
    for (int nt = 0; nt < 2; ++nt) {
      int cib  = ch * 32 + nt * 16 + n;                   // col-in-block 0..63
      int gcol = (cib >> 4) * U_ + blk * 16 + (cib & 15); // gate*4096 + unit
#pragma unroll
      for (int s = 0; s < 16; ++s) {
        half8 th, tl;
#pragma unroll
        for (int i = 0; i < 8; ++i) {
          int k = s * 32 + q * 8 + i;                     // 0..511 within half
          _Float16 hi, lo;
          split_h(Wsrc[(size_t)k * G4 + gcol], hi, lo);
          th[i] = hi; tl[i] = lo;
        }
        bhi[nt][s] = th;
        blo[nt][s] = tl;
      }
    }
  }
  gsync_heavy(bar);   // publish PT device-wide; caches clean after this

  // ---- time loop ------------------------------------------------------
  for (int t = 0; t < S_; ++t) {
    // stage x_t (k<512, normal loads) and h (k>=512, sc1 loads) into LDS
#pragma unroll
    for (int it = 0; it < 16; ++it) {
      int c = tid + it * NTHR;          // 0..4095 chunks of 8
      int b = c >> 7, kc = c & 127;
      int kg = kc << 3;
      float f[8];
      if (kg < D_) {                    // wave-uniform branch (kc<64 per wave)
        const float* src = x + (size_t)(b * S_ + t) * D_ + kg;
        float4 f0 = *(const float4*)src;
        float4 f1 = *(const float4*)(src + 4);
        f[0] = f0.x; f[1] = f0.y; f[2] = f0.z; f[3] = f0.w;
        f[4] = f1.x; f[5] = f1.y; f[6] = f1.z; f[7] = f1.w;
      } else {
        const float* src = hbuf + b * PJ + (kg - D_);
        float2 g0 = ldg_dev8(src);
        float2 g1 = ldg_dev8(src + 2);
        float2 g2 = ldg_dev8(src + 4);
        float2 g3 = ldg_dev8(src + 6);
        f[0] = g0.x; f[1] = g0.y; f[2] = g1.x; f[3] = g1.y;
        f[4] = g2.x; f[5] = g2.y; f[6] = g3.x; f[7] = g3.y;
      }
      half8 th, tl;
#pragma unroll
      for (int i = 0; i < 8; ++i) {
        _Float16 hi, lo;
        split_h(f[i], hi, lo);
        th[i] = hi; tl[i] = lo;
      }
      *(half8*)(xh_hi + b * PITCH + kg) = th;
      *(half8*)(xh_lo + b * PITCH + kg) = tl;
    }
    __syncthreads();

    // phase A: z-slice via split-fp16 MFMA.
    {
      floatx4 acc00 = {0.f, 0.f, 0.f, 0.f};
      floatx4 acc01 = acc00, acc10 = acc00, acc11 = acc00;
      floatx4 accL00 = acc00, accL01 = acc00, accL10 = acc00, accL11 = acc00;
      const int m_ = lane & 15, q = lane >> 4;
      const int kb = kh * D_;
#pragma unroll
      for (int s = 0; s < 16; ++s) {
        int ko = kb + s * 32 + q * 8;
        half8 ah0 = *(const half8*)(xh_hi + m_ * PITCH + ko);
        half8 ah1 = *(const half8*)(xh_hi + (16 + m_) * PITCH + ko);
        half8 al0 = *(const half8*)(xh_lo + m_ * PITCH + ko);
        half8 al1 = *(const half8*)(xh_lo + (16 + m_) * PITCH + ko);
        acc00 = __builtin_amdgcn_mfma_f32_16x16x32_f16(ah0, bhi[0][s], acc00, 0, 0, 0);
        acc01 = __builtin_amdgcn_mfma_f32_16x16x32_f16(ah0, bhi[1][s], acc01, 0, 0, 0);
        acc10 = __builtin_amdgcn_mfma_f32_16x16x32_f16(ah1, bhi[0][s], acc10, 0, 0, 0);
        acc11 = __builtin_amdgcn_mfma_f32_16x16x32_f16(ah1, bhi[1][s], acc11, 0, 0, 0);
        accL00 = __builtin_amdgcn_mfma_f32_16x16x32_f16(ah0, blo[0][s], accL00, 0, 0, 0);
        accL01 = __builtin_amdgcn_mfma_f32_16x16x32_f16(ah0, blo[1][s], accL01, 0, 0, 0);
        accL10 = __builtin_amdgcn_mfma_f32_16x16x32_f16(ah1, blo[0][s], accL10, 0, 0, 0);
        accL11 = __builtin_amdgcn_mfma_f32_16x16x32_f16(ah1, blo[1][s], accL11, 0, 0, 0);
        accL00 = __builtin_amdgcn_mfma_f32_16x16x32_f16(al0, bhi[0][s], accL00, 0, 0, 0);
        accL01 = __builtin_amdgcn_mfma_f32_16x16x32_f16(al0, bhi[1][s], accL01, 0, 0, 0);
        accL10 = __builtin_amdgcn_mfma_f32_16x16x32_f16(al1, bhi[0][s], accL10, 0, 0, 0);
        accL11 = __builtin_amdgcn_mfma_f32_16x16x32_f16(al1, bhi[1][s], accL11, 0, 0, 0);
      }
      // D-frag: col=lane&15, row=quad*4+reg. zb[kh][col][batch].
      int n  = lane & 15;
      int c0 = ch * 32 + n, c1 = ch * 32 + 16 + n;
      int r0 = q * 4,       r1 = 16 + q * 4;
#pragma unroll
      for (int i = 0; i < 4; ++i) {
        zb[kh][c0][r0 + i] = acc00[i] + accL00[i] * LINV;
        zb[kh][c1][r0 + i] = acc01[i] + accL01[i] * LINV;
        zb[kh][c0][r1 + i] = acc10[i] + accL10[i] * LINV;
        zb[kh][c1][r1 + i] = acc11[i] + accL11[i] * LINV;
      }
    }
    __syncthreads();

    // gates + cell update (block-local), hpre -> global via sc1 stores
#pragma unroll
    for (int pp = 0; pp < 2; ++pp) {
      int p = tid + pp * NTHR;          // 0..511
      int b = p >> 4, j = p & 15;       // batch, unit-in-block
      float zi = zb[0][j][b]      + zb[1][j][b]      + biasL[j];
      float zf = zb[0][16 + j][b] + zb[1][16 + j][b] + biasL[16 + j];
      float zc = zb[0][32 + j][b] + zb[1][32 + j][b] + biasL[32 + j];
      float zo = zb[0][48 + j][b] + zb[1][48 + j][b] + biasL[48 + j];
      float ig = fminf(fmaxf(0.2f * zi + 0.5f, 0.f), 1.f);
      float fg = fminf(fmaxf(0.2f * zf + 0.5f, 0.f), 1.f);
      float og = fminf(fmaxf(0.2f * zo + 0.5f, 0.f), 1.f);
      float cn = fg * cst[p] + ig * tanhf(zc);
      float hp = og * tanhf(cn);                 // uses UNCLIPPED c
      cst[p] = fminf(fmaxf(cn, -3.f), 3.f);      // cell clip
      stg_dev4(hpre + b * U_ + blk * 16 + j, hp);
    }
    gsync(bar);   // hpre device-visible (sc1 write-through + vmcnt drain)

    // phase B (64 consumer blocks, 8 cols each, exact fp32):
    // out[b][pc] = clip(sum_k hpre[b][k]*PT[pc][k], +-3)
    if (blk < NCONS) {
      const int col = lane >> 3;        // 0..7 col-in-block
      const int kl  = lane & 7;         // 0..7 k-slice
      const float* prow = PT + (size_t)(blk * CPB + col) * U_;
#pragma unroll 1
      for (int bi = 0; bi < 8; ++bi) {
        const int b = (w << 3) + bi;    // wave w owns batches w*8..w*8+7
        const float* hrow = hpre + b * U_;
        float a0 = 0.f, a1 = 0.f, a2 = 0.f, a3 = 0.f;
        float a4 = 0.f, a5 = 0.f, a6 = 0.f, a7 = 0.f;
#pragma unroll 4
        for (int it = 0; it < 64; ++it) {
          int k = it * 64 + kl * 8;     // consecutive lanes -> consecutive k
          float2 h0 = ldg_dev8(hrow + k);
          float2 h1 = ldg_dev8(hrow + k + 2);
          float2 h2 = ldg_dev8(hrow + k + 4);
          float2 h3 = ldg_dev8(hrow + k + 6);
          float4 p0 = *(const float4*)(prow + k);
          float4 p1 = *(const float4*)(prow + k + 4);
          a0 = fmaf(h0.x, p0.x, a0); a1 = fmaf(h0.y, p0.y, a1);
          a2 = fmaf(h1.x, p0.z, a2); a3 = fmaf(h1.y, p0.w, a3);
          a4 = fmaf(h2.x, p1.x, a4); a5 = fmaf(h2.y, p1.y, a5);
          a6 = fmaf(h3.x, p1.z, a6); a7 = fmaf(h3.y, p1.w, a7);
        }
        float a = ((a0 + a1) + (a2 + a3)) + ((a4 + a5) + (a6 + a7));
        a += __shfl_xor(a, 1, 64);      // butterfly over 8 kl-lanes
        a += __shfl_xor(a, 2, 64);
        a += __shfl_xor(a, 4, 64);
        if (kl == 0) {
          float h = fminf(fmaxf(a, -3.f), 3.f);
          int pc = blk * CPB + col;
          out[(size_t)(b * S_ + t) * PJ + pc] = h;   // normal store (own lines)
          stg_dev4(hbuf + b * PJ + pc, h);           // sc1: next-step staging
        }
      }
    }
    gsync(bar);   // h device-visible before next step's staging
  }
}

extern "C" void kernel_launch(void* const* d_in, const int* in_sizes, int n_in,
                              void* d_out, int out_size, void* d_ws, size_t ws_size,
                              hipStream_t stream) {
  const float* x_   = (const float*)d_in[0];
  const float* Wk   = (const float*)d_in[1];
  const float* R_   = (const float*)d_in[2];
  const float* bias = (const float*)d_in[3];
  const float* P_   = (const float*)d_in[4];
  float* out = (float*)d_out;

  unsigned char* ws = (unsigned char*)d_ws;
  unsigned* bar = (unsigned*)ws;                           // @0      (1 KB)
  float* hbuf   = (float*)(ws + 1024);                     // 64 KB
  float* hpre   = (float*)(ws + 1024 + 65536);             // 512 KB
  float* PT     = (float*)(ws + 1024 + 65536 + 524288);    // 8 MB

  // zero barrier counter + initial h state every launch
  hipMemsetAsync(d_ws, 0, 1024 + 65536, stream);

  lstm_persistent<<<dim3(NBLK), dim3(NTHR), 0, stream>>>(
      x_, Wk, R_, bias, P_, out, bar, hbuf, hpre, PT);
}

// Round 6
// 18939.352 us; speedup vs baseline: 1.0843x; 1.0843x over previous
//
#include <hip/hip_runtime.h>

// LSTM-with-projection (ELMo LSTMP), persistent-kernel, fp32-class precision.
// Round 6 = round 5 with the s_sleep(const) compile fix.
//  - Coherence: producers sc1-STORE shared state (write-through, no dirty L2);
//    consumers use NORMAL loads after acquire-only fence (buffer_inv, no wbl2)
//    -> per-XCD L2 sharing of hpre/hbuf/x/PT returns.
//  - Barrier: two-level arrival (32 group counters -> 1 global), release flag
//    on its own cache line, fixed-ladder s_sleep polling.
//  - Occupancy: 512 threads (8 waves/CU). LDS 102KB via 2-chunk k staging
//    (x-chunk then h-chunk), MFMA accumulators live across chunks.

#define NBLK 256
#define NTHR 512
#define B_   32
#define S_   128
#define D_   512
#define U_   4096
#define PJ   512
#define G4   16384
#define PITC 520      // xh row pitch (fp16 elems) per 512-k chunk (+8 pad)
#define LSCALE 2048.0f
#define LINV   4.8828125e-4f   // 1/2048
#define NCONS 64      // phase-B consumer blocks
#define CPB   8       // projection cols per consumer

typedef __attribute__((ext_vector_type(8))) _Float16 half8;
typedef __attribute__((ext_vector_type(4))) float floatx4;

__device__ __forceinline__ void split_h(float f, _Float16& hi, _Float16& lo) {
  _Float16 h = (_Float16)f;                  // RTNE
  hi = h;
  lo = (_Float16)((f - (float)h) * LSCALE);  // residual x2048: fp16-normal
}

// device-visible write-through store (sc1): no dirty L2 lines ever
__device__ __forceinline__ void stg_dev(float* p, float v) {
  __hip_atomic_store(p, v, __ATOMIC_RELAXED, __HIP_MEMORY_SCOPE_AGENT);
}

// Two-level grid barrier, epoch-based.
//  grp: 32 counters, one per 8-block group, each on its own 128B line
//  gcnt: global counter (own line); rel: release flag (own line)
// First __syncthreads drains vmcnt(0) -> all sc1 stores device-visible before
// arrival. Trailing acquire fence = buffer_inv (drop stale clean L2 lines).
__device__ __forceinline__ void gsync(unsigned* grp, unsigned* gcnt,
                                      unsigned* rel, unsigned ep) {
  __syncthreads();
  if (threadIdx.x == 0) {
    unsigned g = blockIdx.x >> 3;
    unsigned old = __hip_atomic_fetch_add(&grp[g * 32], 1u,
                       __ATOMIC_RELAXED, __HIP_MEMORY_SCOPE_AGENT);
    if (old == ep * 8u - 1u) {                 // last in group
      unsigned o2 = __hip_atomic_fetch_add(gcnt, 1u,
                        __ATOMIC_RELAXED, __HIP_MEMORY_SCOPE_AGENT);
      if (o2 == ep * 32u - 1u)                 // last group -> release
        __hip_atomic_store(rel, ep, __ATOMIC_RELAXED,
                           __HIP_MEMORY_SCOPE_AGENT);
    }
    // fixed-ladder backoff (s_sleep arg must be a compile-time constant)
    if (__hip_atomic_load(rel, __ATOMIC_RELAXED,
                          __HIP_MEMORY_SCOPE_AGENT) < ep) {
      __builtin_amdgcn_s_sleep(1);
      if (__hip_atomic_load(rel, __ATOMIC_RELAXED,
                            __HIP_MEMORY_SCOPE_AGENT) < ep) {
        __builtin_amdgcn_s_sleep(2);
        while (__hip_atomic_load(rel, __ATOMIC_RELAXED,
                                 __HIP_MEMORY_SCOPE_AGENT) < ep)
          __builtin_amdgcn_s_sleep(8);         // ~512 cyc steady poll
      }
    }
  }
  __syncthreads();
  __builtin_amdgcn_fence(__ATOMIC_ACQUIRE, "agent");   // inv, no wbl2
}

__global__ __launch_bounds__(NTHR, 2)
void lstm_persistent(const float* __restrict__ x,
                     const float* __restrict__ Wk,
                     const float* __restrict__ R,
                     const float* __restrict__ bias,
                     const float* __restrict__ P,
                     float* __restrict__ out,
                     unsigned* __restrict__ grp,
                     unsigned* __restrict__ gcnt,
                     unsigned* __restrict__ rel,
                     float* __restrict__ hbuf,   // [32][512] f32 (zeroed)
                     float* __restrict__ hpre,   // [32][4096] f32
                     float* __restrict__ PT)     // [512][4096] f32 = P^T
{
  __shared__ __align__(16) _Float16 xh_hi[B_ * PITC];  // 33280 B
  __shared__ __align__(16) _Float16 xh_lo[B_ * PITC];  // 33280 B
  __shared__ __align__(16) float zb[4][64][33];        // 33792 B
  __shared__ float cst[512];                           //  2048 B
  __shared__ float biasL[64];                          // total ~102 KB

  const int tid  = threadIdx.x;
  const int blk  = blockIdx.x;
  const int lane = tid & 63;
  const int w    = tid >> 6;   // wave 0..7
  const int ch   = w & 1;      // col-half: 0 -> cols 0..31, 1 -> 32..63
  const int sq   = w >> 1;     // k-quarter within chunk: 4 s-iters each

  // ---- one-time setup -------------------------------------------------
  if (tid < 64) {
    int g = tid >> 4, j = tid & 15;
    biasL[tid] = bias[g * U_ + blk * 16 + j];
  }
  cst[tid] = 0.f;

  // transpose our 16 unit-rows of P into PT: PT[c][k] = P[k][c]
  for (int i = tid; i < 16 * PJ; i += NTHR) {
    int c  = i >> 4;
    int kr = i & 15;
    int k  = blk * 16 + kr;
    PT[(size_t)c * U_ + k] = P[(size_t)k * PJ + c];
  }

  // Weight B-fragments (split fp16) into registers.
  // B-frag (16x16x32): lane holds B[k=quad*8+j][n=lane&15].
  // bhi[nt][chunk][u]: chunk 0 = Wk, chunk 1 = R; u = s-iter within quarter.
  half8 bhi[2][2][4], blo[2][2][4];
  {
    const int n = lane & 15, q = lane >> 4;
#pragma unroll
    for (int c = 0; c < 2; ++c) {
      const float* Wsrc = c ? R : Wk;
#pragma unroll
      for (int nt = 0; nt < 2; ++nt) {
        int cib  = ch * 32 + nt * 16 + n;                   // col-in-block
        int gcol = (cib >> 4) * U_ + blk * 16 + (cib & 15); // gate*4096+unit
#pragma unroll
        for (int u = 0; u < 4; ++u) {
          half8 th, tl;
#pragma unroll
          for (int i = 0; i < 8; ++i) {
            int k = (sq * 4 + u) * 32 + q * 8 + i;          // 0..511
            _Float16 hi, lo;
            split_h(Wsrc[(size_t)k * G4 + gcol], hi, lo);
            th[i] = hi; tl[i] = lo;
          }
          bhi[nt][c][u] = th;
          blo[nt][c][u] = tl;
        }
      }
    }
  }
  unsigned ep = 1;
  __threadfence();                      // release: wbl2 (publish PT)
  gsync(grp, gcnt, rel, ep);            // heavy init barrier

  // ---- time loop ------------------------------------------------------
  for (int t = 0; t < S_; ++t) {
    floatx4 acc00 = {0.f, 0.f, 0.f, 0.f};
    floatx4 acc01 = acc00, acc10 = acc00, acc11 = acc00;
    floatx4 accL00 = acc00, accL01 = acc00, accL10 = acc00, accL11 = acc00;
    const int m_ = lane & 15, q = lane >> 4;

#pragma unroll
    for (int c = 0; c < 2; ++c) {
      // stage chunk c: c==0 -> x_t[32][512], c==1 -> h[32][512]
#pragma unroll
      for (int it = 0; it < 4; ++it) {
        int c8 = tid + it * NTHR;       // 0..2047 groups of 8
        int b  = c8 >> 6;
        int kg = (c8 & 63) << 3;        // 0..511
        const float* src = (c == 0) ? (x + (size_t)(b * S_ + t) * D_ + kg)
                                    : (hbuf + b * PJ + kg);
        float4 f0 = *(const float4*)src;
        float4 f1 = *(const float4*)(src + 4);
        half8 th, tl;
        _Float16 hi, lo;
        split_h(f0.x, hi, lo); th[0] = hi; tl[0] = lo;
        split_h(f0.y, hi, lo); th[1] = hi; tl[1] = lo;
        split_h(f0.z, hi, lo); th[2] = hi; tl[2] = lo;
        split_h(f0.w, hi, lo); th[3] = hi; tl[3] = lo;
        split_h(f1.x, hi, lo); th[4] = hi; tl[4] = lo;
        split_h(f1.y, hi, lo); th[5] = hi; tl[5] = lo;
        split_h(f1.z, hi, lo); th[6] = hi; tl[6] = lo;
        split_h(f1.w, hi, lo); th[7] = hi; tl[7] = lo;
        *(half8*)(xh_hi + b * PITC + kg) = th;
        *(half8*)(xh_lo + b * PITC + kg) = tl;
      }
      __syncthreads();

      // MFMA chunk c: 4 s-iters per wave, accumulate across chunks.
#pragma unroll
      for (int u = 0; u < 4; ++u) {
        int ko = (sq * 4 + u) * 32 + q * 8;
        half8 ah0 = *(const half8*)(xh_hi + m_ * PITC + ko);
        half8 ah1 = *(const half8*)(xh_hi + (16 + m_) * PITC + ko);
        half8 al0 = *(const half8*)(xh_lo + m_ * PITC + ko);
        half8 al1 = *(const half8*)(xh_lo + (16 + m_) * PITC + ko);
        acc00 = __builtin_amdgcn_mfma_f32_16x16x32_f16(ah0, bhi[0][c][u], acc00, 0, 0, 0);
        acc01 = __builtin_amdgcn_mfma_f32_16x16x32_f16(ah0, bhi[1][c][u], acc01, 0, 0, 0);
        acc10 = __builtin_amdgcn_mfma_f32_16x16x32_f16(ah1, bhi[0][c][u], acc10, 0, 0, 0);
        acc11 = __builtin_amdgcn_mfma_f32_16x16x32_f16(ah1, bhi[1][c][u], acc11, 0, 0, 0);
        accL00 = __builtin_amdgcn_mfma_f32_16x16x32_f16(ah0, blo[0][c][u], accL00, 0, 0, 0);
        accL01 = __builtin_amdgcn_mfma_f32_16x16x32_f16(ah0, blo[1][c][u], accL01, 0, 0, 0);
        accL10 = __builtin_amdgcn_mfma_f32_16x16x32_f16(ah1, blo[0][c][u], accL10, 0, 0, 0);
        accL11 = __builtin_amdgcn_mfma_f32_16x16x32_f16(ah1, blo[1][c][u], accL11, 0, 0, 0);
        accL00 = __builtin_amdgcn_mfma_f32_16x16x32_f16(al0, bhi[0][c][u], accL00, 0, 0, 0);
        accL01 = __builtin_amdgcn_mfma_f32_16x16x32_f16(al0, bhi[1][c][u], accL01, 0, 0, 0);
        accL10 = __builtin_amdgcn_mfma_f32_16x16x32_f16(al1, bhi[0][c][u], accL10, 0, 0, 0);
        accL11 = __builtin_amdgcn_mfma_f32_16x16x32_f16(al1, bhi[1][c][u], accL11, 0, 0, 0);
      }
      __syncthreads();   // before chunk 1 overwrites xh / before gates
    }

    // D-frag: col=lane&15, row=quad*4+reg. zb[sq][col][batch].
    {
      int n  = lane & 15;
      int c0 = ch * 32 + n, c1 = ch * 32 + 16 + n;
      int r0 = q * 4,       r1 = 16 + q * 4;
#pragma unroll
      for (int i = 0; i < 4; ++i) {
        zb[sq][c0][r0 + i] = acc00[i] + accL00[i] * LINV;
        zb[sq][c1][r0 + i] = acc01[i] + accL01[i] * LINV;
        zb[sq][c0][r1 + i] = acc10[i] + accL10[i] * LINV;
        zb[sq][c1][r1 + i] = acc11[i] + accL11[i] * LINV;
      }
    }
    __syncthreads();

    // gates + cell update (block-local), hpre -> global sc1 (write-through)
    {
      int p = tid;                      // 0..511
      int b = p >> 4, j = p & 15;       // batch, unit-in-block
      float zi = zb[0][j][b] + zb[1][j][b] + zb[2][j][b] + zb[3][j][b] + biasL[j];
      float zf = zb[0][16+j][b] + zb[1][16+j][b] + zb[2][16+j][b] + zb[3][16+j][b] + biasL[16+j];
      float zc = zb[0][32+j][b] + zb[1][32+j][b] + zb[2][32+j][b] + zb[3][32+j][b] + biasL[32+j];
      float zo = zb[0][48+j][b] + zb[1][48+j][b] + zb[2][48+j][b] + zb[3][48+j][b] + biasL[48+j];
      float ig = fminf(fmaxf(0.2f * zi + 0.5f, 0.f), 1.f);
      float fg = fminf(fmaxf(0.2f * zf + 0.5f, 0.f), 1.f);
      float og = fminf(fmaxf(0.2f * zo + 0.5f, 0.f), 1.f);
      float cn = fg * cst[p] + ig * tanhf(zc);
      float hp = og * tanhf(cn);                 // uses UNCLIPPED c
      cst[p] = fminf(fmaxf(cn, -3.f), 3.f);      // cell clip
      stg_dev(hpre + b * U_ + blk * 16 + j, hp);
    }
    gsync(grp, gcnt, rel, ++ep);   // hpre visible; acquire-inv for consumers

    // phase B (64 consumer blocks, 8 cols each, exact fp32, NORMAL loads):
    // out[b][pc] = clip(sum_k hpre[b][k]*PT[pc][k], +-3)
    if (blk < NCONS) {
      const int col = lane >> 3;        // 0..7 col-in-block
      const int kl  = lane & 7;         // 0..7 k-slice
      const float* prow = PT + (size_t)(blk * CPB + col) * U_;
      for (int bi = 0; bi < 4; ++bi) {
        const int b = (w << 2) + bi;    // wave w owns batches w*4..w*4+3
        const float* hrow = hpre + b * U_;
        float a0 = 0.f, a1 = 0.f, a2 = 0.f, a3 = 0.f;
        float a4 = 0.f, a5 = 0.f, a6 = 0.f, a7 = 0.f;
#pragma unroll 4
        for (int it = 0; it < 32; ++it) {
          int k = it * 128 + kl * 16;   // each lane: 16 consecutive floats
          float4 h0 = *(const float4*)(hrow + k);
          float4 h1 = *(const float4*)(hrow + k + 4);
          float4 h2 = *(const float4*)(hrow + k + 8);
          float4 h3 = *(const float4*)(hrow + k + 12);
          float4 p0 = *(const float4*)(prow + k);
          float4 p1 = *(const float4*)(prow + k + 4);
          float4 p2 = *(const float4*)(prow + k + 8);
          float4 p3 = *(const float4*)(prow + k + 12);
          a0 = fmaf(h0.x, p0.x, a0); a1 = fmaf(h0.y, p0.y, a1);
          a2 = fmaf(h0.z, p0.z, a2); a3 = fmaf(h0.w, p0.w, a3);
          a4 = fmaf(h1.x, p1.x, a4); a5 = fmaf(h1.y, p1.y, a5);
          a6 = fmaf(h1.z, p1.z, a6); a7 = fmaf(h1.w, p1.w, a7);
          a0 = fmaf(h2.x, p2.x, a0); a1 = fmaf(h2.y, p2.y, a1);
          a2 = fmaf(h2.z, p2.z, a2); a3 = fmaf(h2.w, p2.w, a3);
          a4 = fmaf(h3.x, p3.x, a4); a5 = fmaf(h3.y, p3.y, a5);
          a6 = fmaf(h3.z, p3.z, a6); a7 = fmaf(h3.w, p3.w, a7);
        }
        float a = ((a0 + a1) + (a2 + a3)) + ((a4 + a5) + (a6 + a7));
        a += __shfl_xor(a, 1, 64);      // butterfly over 8 kl-lanes
        a += __shfl_xor(a, 2, 64);
        a += __shfl_xor(a, 4, 64);
        if (kl == 0) {
          float h = fminf(fmaxf(a, -3.f), 3.f);
          int pc = blk * CPB + col;
          stg_dev(out + (size_t)(b * S_ + t) * PJ + pc, h);
          stg_dev(hbuf + b * PJ + pc, h);
        }
      }
    }
    gsync(grp, gcnt, rel, ++ep);   // h visible before next step's staging
  }
}

extern "C" void kernel_launch(void* const* d_in, const int* in_sizes, int n_in,
                              void* d_out, int out_size, void* d_ws, size_t ws_size,
                              hipStream_t stream) {
  const float* x_   = (const float*)d_in[0];
  const float* Wk   = (const float*)d_in[1];
  const float* R_   = (const float*)d_in[2];
  const float* bias = (const float*)d_in[3];
  const float* P_   = (const float*)d_in[4];
  float* out = (float*)d_out;

  unsigned char* ws = (unsigned char*)d_ws;
  unsigned* grp  = (unsigned*)ws;                     // 32 x 128B lines (4KB)
  unsigned* gcnt = (unsigned*)(ws + 4096);            // own line
  unsigned* rel  = (unsigned*)(ws + 4096 + 128);      // own line
  float* hbuf    = (float*)(ws + 8192);               // 64 KB
  float* hpre    = (float*)(ws + 8192 + 65536);       // 512 KB
  float* PT      = (float*)(ws + 8192 + 65536 + 524288);  // 8 MB

  // zero barrier state + initial h every launch
  (void)hipMemsetAsync(d_ws, 0, 8192 + 65536, stream);

  lstm_persistent<<<dim3(NBLK), dim3(NTHR), 0, stream>>>(
      x_, Wk, R_, bias, P_, out, grp, gcnt, rel, hbuf, hpre, PT);
}

// Round 7
// 7706.055 us; speedup vs baseline: 2.6649x; 2.4577x over previous
//
#include <hip/hip_runtime.h>

// LSTM-with-projection (ELMo LSTMP), persistent-kernel, fp32-class precision.
// Round 7: phase B was a VALU dot-product pushing ~8MB/step through each
// consumer CU's L1->RF path (~50us/step while the grid waits). Rebuilt as a
// split-fp16 MFMA GEMM:
//  - 32 consumer blocks x 16 cols; P-fragments in registers (init-time).
//  - hpre stored as split-fp16 hi/lo planes; each wave owns a private K=512
//    slice -> A-frags loaded DIRECTLY from global (no redundancy, no LDS
//    staging); cross-wave K-reduce via 16KB LDS.
//  - Coherence: sc1 stores for shared state + acquire-inv in barrier.
//  - Phase A unchanged (split-fp16 MFMA, weights in registers) - it passed.

#define NBLK 256
#define NTHR 512
#define B_   32
#define S_   128
#define D_   512
#define U_   4096
#define PJ   512
#define G4   16384
#define PITC 520      // xh row pitch (fp16 elems) per 512-k chunk (+8 pad)
#define LSCALE 2048.0f
#define LINV   4.8828125e-4f   // 1/2048
#define NCONS 32      // phase-B consumer blocks
#define CPBC  16      // projection cols per consumer

typedef __attribute__((ext_vector_type(8))) _Float16 half8;
typedef __attribute__((ext_vector_type(4))) float floatx4;

__device__ __forceinline__ void split_h(float f, _Float16& hi, _Float16& lo) {
  _Float16 h = (_Float16)f;                  // RTNE
  hi = h;
  lo = (_Float16)((f - (float)h) * LSCALE);  // residual x2048: fp16-normal
}

// device-visible write-through stores (sc1): no dirty L2 lines ever
__device__ __forceinline__ void stg_dev(float* p, float v) {
  __hip_atomic_store(p, v, __ATOMIC_RELAXED, __HIP_MEMORY_SCOPE_AGENT);
}
__device__ __forceinline__ void stg_dev_u32(unsigned* p, unsigned v) {
  __hip_atomic_store(p, v, __ATOMIC_RELAXED, __HIP_MEMORY_SCOPE_AGENT);
}

// Two-level grid barrier, epoch-based. First __syncthreads drains vmcnt(0)
// -> all sc1 stores device-visible before arrival. Trailing acquire fence
// = buffer_inv (drop stale clean L1/L2 lines), no wbl2.
__device__ __forceinline__ void gsync(unsigned* grp, unsigned* gcnt,
                                      unsigned* rel, unsigned ep) {
  __syncthreads();
  if (threadIdx.x == 0) {
    unsigned g = blockIdx.x >> 3;
    unsigned old = __hip_atomic_fetch_add(&grp[g * 32], 1u,
                       __ATOMIC_RELAXED, __HIP_MEMORY_SCOPE_AGENT);
    if (old == ep * 8u - 1u) {                 // last in group
      unsigned o2 = __hip_atomic_fetch_add(gcnt, 1u,
                        __ATOMIC_RELAXED, __HIP_MEMORY_SCOPE_AGENT);
      if (o2 == ep * 32u - 1u)                 // last group -> release
        __hip_atomic_store(rel, ep, __ATOMIC_RELAXED,
                           __HIP_MEMORY_SCOPE_AGENT);
    }
    if (__hip_atomic_load(rel, __ATOMIC_RELAXED,
                          __HIP_MEMORY_SCOPE_AGENT) < ep) {
      __builtin_amdgcn_s_sleep(1);
      while (__hip_atomic_load(rel, __ATOMIC_RELAXED,
                               __HIP_MEMORY_SCOPE_AGENT) < ep)
        __builtin_amdgcn_s_sleep(4);           // ~256 cyc steady poll
    }
  }
  __syncthreads();
  __builtin_amdgcn_fence(__ATOMIC_ACQUIRE, "agent");
}

__global__ __launch_bounds__(NTHR, 2)
void lstm_persistent(const float* __restrict__ x,
                     const float* __restrict__ Wk,
                     const float* __restrict__ R,
                     const float* __restrict__ bias,
                     const float* __restrict__ P,
                     float* __restrict__ out,
                     unsigned* __restrict__ grp,
                     unsigned* __restrict__ gcnt,
                     unsigned* __restrict__ rel,
                     float* __restrict__ hbuf,            // [32][512] f32
                     unsigned short* __restrict__ hpreH,  // [32][4096] fp16 hi
                     unsigned short* __restrict__ hpreL)  // [32][4096] fp16 lo
{
  // LDS arena: phase A (xh 66.5K + zb 33K) and phase B (red 16K) disjoint use
  __shared__ __align__(16) char smem[100352 + 16384];
  _Float16* xh_hi = (_Float16*)smem;                    // 32*520 halves
  _Float16* xh_lo = xh_hi + B_ * PITC;                  // @33280
  float (*zb)[64][33] = (float (*)[64][33])(smem + 66560);  // [4][64][33]
  float* red = (float*)(smem + 100352);                 // [8][32][16]
  __shared__ float cst[512];
  __shared__ float biasL[64];

  const int tid  = threadIdx.x;
  const int blk  = blockIdx.x;
  const int lane = tid & 63;
  const int w    = tid >> 6;   // wave 0..7
  const int ch   = w & 1;      // phase A col-half
  const int sq   = w >> 1;     // phase A k-quarter (4 s-iters)

  // ---- one-time setup -------------------------------------------------
  if (tid < 64) {
    int g = tid >> 4, j = tid & 15;
    biasL[tid] = bias[g * U_ + blk * 16 + j];
  }
  cst[tid] = 0.f;

  // Phase A weight B-fragments (split fp16) into registers.
  half8 bhi[2][2][4], blo[2][2][4];
  {
    const int n = lane & 15, q = lane >> 4;
#pragma unroll
    for (int c = 0; c < 2; ++c) {
      const float* Wsrc = c ? R : Wk;
#pragma unroll
      for (int nt = 0; nt < 2; ++nt) {
        int cib  = ch * 32 + nt * 16 + n;
        int gcol = (cib >> 4) * U_ + blk * 16 + (cib & 15);
#pragma unroll
        for (int u = 0; u < 4; ++u) {
          half8 th, tl;
#pragma unroll
          for (int i = 0; i < 8; ++i) {
            int k = (sq * 4 + u) * 32 + q * 8 + i;
            _Float16 hi, lo;
            split_h(Wsrc[(size_t)k * G4 + gcol], hi, lo);
            th[i] = hi; tl[i] = lo;
          }
          bhi[nt][c][u] = th;
          blo[nt][c][u] = tl;
        }
      }
    }
  }

  // Phase B P-fragments (split fp16) into registers (consumers only).
  // B-frag (16x16x32): lane holds B[k=quad*8+j][n=lane&15]; wave w owns
  // K-slice [w*512, (w+1)*512), 16 kc-chunks of 32.
  half8 pbh[16], pbl[16];
  if (blk < NCONS) {
    const int n = lane & 15, q = lane >> 4;
    const int colg = blk * CPBC + n;
#pragma unroll
    for (int kc = 0; kc < 16; ++kc) {
      half8 th, tl;
#pragma unroll
      for (int i = 0; i < 8; ++i) {
        int k = w * 512 + kc * 32 + q * 8 + i;
        _Float16 hi, lo;
        split_h(P[(size_t)k * PJ + colg], hi, lo);
        th[i] = hi; tl[i] = lo;
      }
      pbh[kc] = th;
      pbl[kc] = tl;
    }
  }

  unsigned ep = 0;

  // ---- time loop ------------------------------------------------------
  for (int t = 0; t < S_; ++t) {
    floatx4 acc00 = {0.f, 0.f, 0.f, 0.f};
    floatx4 acc01 = acc00, acc10 = acc00, acc11 = acc00;
    floatx4 accL00 = acc00, accL01 = acc00, accL10 = acc00, accL11 = acc00;
    const int m_ = lane & 15, q = lane >> 4;

    // phase A: z = [x_t;h] @ [Wk;R], 2 k-chunks of 512
#pragma unroll
    for (int c = 0; c < 2; ++c) {
#pragma unroll
      for (int it = 0; it < 4; ++it) {
        int c8 = tid + it * NTHR;
        int b  = c8 >> 6;
        int kg = (c8 & 63) << 3;
        const float* src = (c == 0) ? (x + (size_t)(b * S_ + t) * D_ + kg)
                                    : (hbuf + b * PJ + kg);
        float4 f0 = *(const float4*)src;
        float4 f1 = *(const float4*)(src + 4);
        half8 th, tl;
        _Float16 hi, lo;
        split_h(f0.x, hi, lo); th[0] = hi; tl[0] = lo;
        split_h(f0.y, hi, lo); th[1] = hi; tl[1] = lo;
        split_h(f0.z, hi, lo); th[2] = hi; tl[2] = lo;
        split_h(f0.w, hi, lo); th[3] = hi; tl[3] = lo;
        split_h(f1.x, hi, lo); th[4] = hi; tl[4] = lo;
        split_h(f1.y, hi, lo); th[5] = hi; tl[5] = lo;
        split_h(f1.z, hi, lo); th[6] = hi; tl[6] = lo;
        split_h(f1.w, hi, lo); th[7] = hi; tl[7] = lo;
        *(half8*)(xh_hi + b * PITC + kg) = th;
        *(half8*)(xh_lo + b * PITC + kg) = tl;
      }
      __syncthreads();
#pragma unroll
      for (int u = 0; u < 4; ++u) {
        int ko = (sq * 4 + u) * 32 + q * 8;
        half8 ah0 = *(const half8*)(xh_hi + m_ * PITC + ko);
        half8 ah1 = *(const half8*)(xh_hi + (16 + m_) * PITC + ko);
        half8 al0 = *(const half8*)(xh_lo + m_ * PITC + ko);
        half8 al1 = *(const half8*)(xh_lo + (16 + m_) * PITC + ko);
        acc00 = __builtin_amdgcn_mfma_f32_16x16x32_f16(ah0, bhi[0][c][u], acc00, 0, 0, 0);
        acc01 = __builtin_amdgcn_mfma_f32_16x16x32_f16(ah0, bhi[1][c][u], acc01, 0, 0, 0);
        acc10 = __builtin_amdgcn_mfma_f32_16x16x32_f16(ah1, bhi[0][c][u], acc10, 0, 0, 0);
        acc11 = __builtin_amdgcn_mfma_f32_16x16x32_f16(ah1, bhi[1][c][u], acc11, 0, 0, 0);
        accL00 = __builtin_amdgcn_mfma_f32_16x16x32_f16(ah0, blo[0][c][u], accL00, 0, 0, 0);
        accL01 = __builtin_amdgcn_mfma_f32_16x16x32_f16(ah0, blo[1][c][u], accL01, 0, 0, 0);
        accL10 = __builtin_amdgcn_mfma_f32_16x16x32_f16(ah1, blo[0][c][u], accL10, 0, 0, 0);
        accL11 = __builtin_amdgcn_mfma_f32_16x16x32_f16(ah1, blo[1][c][u], accL11, 0, 0, 0);
        accL00 = __builtin_amdgcn_mfma_f32_16x16x32_f16(al0, bhi[0][c][u], accL00, 0, 0, 0);
        accL01 = __builtin_amdgcn_mfma_f32_16x16x32_f16(al0, bhi[1][c][u], accL01, 0, 0, 0);
        accL10 = __builtin_amdgcn_mfma_f32_16x16x32_f16(al1, bhi[0][c][u], accL10, 0, 0, 0);
        accL11 = __builtin_amdgcn_mfma_f32_16x16x32_f16(al1, bhi[1][c][u], accL11, 0, 0, 0);
      }
      __syncthreads();
    }

    // D-frag -> zb[sq][col][batch]
    {
      int n  = lane & 15;
      int c0 = ch * 32 + n, c1 = ch * 32 + 16 + n;
      int r0 = q * 4,       r1 = 16 + q * 4;
#pragma unroll
      for (int i = 0; i < 4; ++i) {
        zb[sq][c0][r0 + i] = acc00[i] + accL00[i] * LINV;
        zb[sq][c1][r0 + i] = acc01[i] + accL01[i] * LINV;
        zb[sq][c0][r1 + i] = acc10[i] + accL10[i] * LINV;
        zb[sq][c1][r1 + i] = acc11[i] + accL11[i] * LINV;
      }
    }
    __syncthreads();

    // gates + cell update; hpre -> split-fp16 planes (paired u32 sc1 stores)
    {
      int p = tid;                      // 0..511
      int b = p >> 4, j = p & 15;       // batch, unit-in-block
      float zi = zb[0][j][b] + zb[1][j][b] + zb[2][j][b] + zb[3][j][b] + biasL[j];
      float zf = zb[0][16+j][b] + zb[1][16+j][b] + zb[2][16+j][b] + zb[3][16+j][b] + biasL[16+j];
      float zc = zb[0][32+j][b] + zb[1][32+j][b] + zb[2][32+j][b] + zb[3][32+j][b] + biasL[32+j];
      float zo = zb[0][48+j][b] + zb[1][48+j][b] + zb[2][48+j][b] + zb[3][48+j][b] + biasL[48+j];
      float ig = fminf(fmaxf(0.2f * zi + 0.5f, 0.f), 1.f);
      float fg = fminf(fmaxf(0.2f * zf + 0.5f, 0.f), 1.f);
      float og = fminf(fmaxf(0.2f * zo + 0.5f, 0.f), 1.f);
      float cn = fg * cst[p] + ig * tanhf(zc);
      float hp = og * tanhf(cn);                 // uses UNCLIPPED c
      cst[p] = fminf(fmaxf(cn, -3.f), 3.f);      // cell clip

      _Float16 hh, hl;
      split_h(hp, hh, hl);
      unsigned both = (unsigned)__builtin_bit_cast(unsigned short, hh) |
                      ((unsigned)__builtin_bit_cast(unsigned short, hl) << 16);
      unsigned nb = __shfl_xor(both, 1, 64);     // neighbor unit (j^1)
      if ((j & 1) == 0) {
        unsigned idx2 = (unsigned)(b * U_ + blk * 16 + j) >> 1;
        stg_dev_u32((unsigned*)hpreH + idx2, (both & 0xffffu) | (nb << 16));
        stg_dev_u32((unsigned*)hpreL + idx2, (both >> 16) | (nb & 0xffff0000u));
      }
    }
    gsync(grp, gcnt, rel, ++ep);   // hpre visible; acquire-inv for consumers

    // phase B (MFMA GEMM): out[b][col] = clip(hpre @ P, +-3)
    // wave w: K-slice [w*512,+512); A-frags direct from global (16B/lane).
    if (blk < NCONS) {
      floatx4 pa0 = {0.f, 0.f, 0.f, 0.f};
      floatx4 pa1 = pa0, pL0 = pa0, pL1 = pa0;
      const unsigned short* rowH0 = hpreH + m_ * U_ + w * 512;
      const unsigned short* rowH1 = hpreH + (16 + m_) * U_ + w * 512;
      const unsigned short* rowL0 = hpreL + m_ * U_ + w * 512;
      const unsigned short* rowL1 = hpreL + (16 + m_) * U_ + w * 512;
#pragma unroll
      for (int kc = 0; kc < 16; ++kc) {
        int ko = kc * 32 + q * 8;
        half8 ah0 = *(const half8*)(rowH0 + ko);
        half8 ah1 = *(const half8*)(rowH1 + ko);
        half8 al0 = *(const half8*)(rowL0 + ko);
        half8 al1 = *(const half8*)(rowL1 + ko);
        pa0 = __builtin_amdgcn_mfma_f32_16x16x32_f16(ah0, pbh[kc], pa0, 0, 0, 0);
        pa1 = __builtin_amdgcn_mfma_f32_16x16x32_f16(ah1, pbh[kc], pa1, 0, 0, 0);
        pL0 = __builtin_amdgcn_mfma_f32_16x16x32_f16(ah0, pbl[kc], pL0, 0, 0, 0);
        pL1 = __builtin_amdgcn_mfma_f32_16x16x32_f16(ah1, pbl[kc], pL1, 0, 0, 0);
        pL0 = __builtin_amdgcn_mfma_f32_16x16x32_f16(al0, pbh[kc], pL0, 0, 0, 0);
        pL1 = __builtin_amdgcn_mfma_f32_16x16x32_f16(al1, pbh[kc], pL1, 0, 0, 0);
      }
      // partials -> red[w][m][col]; C-frag: col=lane&15, row=q*4+i
      int n = lane & 15;
#pragma unroll
      for (int i = 0; i < 4; ++i) {
        red[(w * 32 + q * 4 + i) * 16 + n]      = pa0[i] + pL0[i] * LINV;
        red[(w * 32 + 16 + q * 4 + i) * 16 + n] = pa1[i] + pL1[i] * LINV;
      }
      __syncthreads();
      // finalize: thread -> (m=tid>>4, col=tid&15); sum 8 wave-partials
      {
        int m = tid >> 4, col = tid & 15;
        float s = 0.f;
#pragma unroll
        for (int ww = 0; ww < 8; ++ww)
          s += red[(ww * 32 + m) * 16 + col];
        float h = fminf(fmaxf(s, -3.f), 3.f);
        int colg = blk * CPBC + col;
        stg_dev(out + (size_t)(m * S_ + t) * PJ + colg, h);
        stg_dev(hbuf + m * PJ + colg, h);
      }
    }
    gsync(grp, gcnt, rel, ++ep);   // h visible before next step's staging
  }
}

extern "C" void kernel_launch(void* const* d_in, const int* in_sizes, int n_in,
                              void* d_out, int out_size, void* d_ws, size_t ws_size,
                              hipStream_t stream) {
  const float* x_   = (const float*)d_in[0];
  const float* Wk   = (const float*)d_in[1];
  const float* R_   = (const float*)d_in[2];
  const float* bias = (const float*)d_in[3];
  const float* P_   = (const float*)d_in[4];
  float* out = (float*)d_out;

  unsigned char* ws = (unsigned char*)d_ws;
  unsigned* grp  = (unsigned*)ws;                     // 32 x 128B lines
  unsigned* gcnt = (unsigned*)(ws + 4096);            // own line
  unsigned* rel  = (unsigned*)(ws + 4096 + 128);      // own line
  float* hbuf    = (float*)(ws + 8192);               // 64 KB
  unsigned short* hpreH = (unsigned short*)(ws + 8192 + 65536);   // 256 KB
  unsigned short* hpreL = (unsigned short*)(ws + 8192 + 65536 + 262144); // 256 KB

  // zero barrier state + initial h every launch
  (void)hipMemsetAsync(d_ws, 0, 8192 + 65536, stream);

  lstm_persistent<<<dim3(NBLK), dim3(NTHR), 0, stream>>>(
      x_, Wk, R_, bias, P_, out, grp, gcnt, rel, hbuf, hpreH, hpreL);
}

// Round 8
// 5702.969 us; speedup vs baseline: 3.6009x; 1.3512x over previous
//
#include <hip/hip_runtime.h>

// LSTM-with-projection (ELMo LSTMP), persistent-kernel, fp32-class precision.
// Round 8: replace 2 full grid barriers (+buffer_inv) with directional flag
// semaphores; zero cache-maintenance in the loop.
//  - Mutable cross-block data (hpre,hbuf,out,flags) via sc1 atomics (LLC-
//    coherent). Read-only (x, weights, P-frags) via normal loads: cached
//    forever (no inv anywhere).
//  - Arrival: 32 parallel group counters -> grpDone[g]; 32 consumers poll
//    lane-parallel. Consumers -> consDone[c]; block0 aggregates + fans out
//    flagB to 32 lines (8 pollers each).
//  - Overlap: x-chunk of phase A runs before the flagB wait, so producers
//    surge into step t+1 while consumers do phase B of step t.
//  - Consumer P-fragments in per-block ws array (split fp16), written+read by
//    the same block (same-CU caches; no fence), normal 16B loads -> no spills.

#define NBLK 256
#define NTHR 512
#define B_   32
#define S_   128
#define D_   512
#define U_   4096
#define PJ   512
#define G4   16384
#define PITC 520
#define LSCALE 2048.0f
#define LINV   4.8828125e-4f   // 1/2048
#define NCONS 32
#define CPBC  16

typedef __attribute__((ext_vector_type(8))) _Float16 half8;
typedef __attribute__((ext_vector_type(4))) float floatx4;

__device__ __forceinline__ void split_h(float f, _Float16& hi, _Float16& lo) {
  _Float16 h = (_Float16)f;                  // RTNE
  hi = h;
  lo = (_Float16)((f - (float)h) * LSCALE);  // residual x2048: fp16-normal
}

// ---- agent-scope (sc1) ops: LLC-coherent, no fences needed ----
__device__ __forceinline__ void stg_dev(float* p, float v) {
  __hip_atomic_store(p, v, __ATOMIC_RELAXED, __HIP_MEMORY_SCOPE_AGENT);
}
__device__ __forceinline__ void stg_dev_u32(unsigned* p, unsigned v) {
  __hip_atomic_store(p, v, __ATOMIC_RELAXED, __HIP_MEMORY_SCOPE_AGENT);
}
__device__ __forceinline__ unsigned ldg_dev_u32(const unsigned* p) {
  return __hip_atomic_load(p, __ATOMIC_RELAXED, __HIP_MEMORY_SCOPE_AGENT);
}
__device__ __forceinline__ float2 ldg_dev8(const float* p) {
  unsigned long long v = __hip_atomic_load((const unsigned long long*)p,
                                           __ATOMIC_RELAXED,
                                           __HIP_MEMORY_SCOPE_AGENT);
  union { unsigned long long u; float2 f; } c; c.u = v; return c.f;
}
__device__ __forceinline__ half8 ld16_dev(const unsigned short* p) {
  unsigned long long a = __hip_atomic_load((const unsigned long long*)p,
                           __ATOMIC_RELAXED, __HIP_MEMORY_SCOPE_AGENT);
  unsigned long long b = __hip_atomic_load((const unsigned long long*)p + 1,
                           __ATOMIC_RELAXED, __HIP_MEMORY_SCOPE_AGENT);
  union { unsigned long long u[2]; half8 h; } c; c.u[0] = a; c.u[1] = b;
  return c.h;
}

__global__ __launch_bounds__(NTHR, 2)
void lstm_persistent(const float* __restrict__ x,
                     const float* __restrict__ Wk,
                     const float* __restrict__ R,
                     const float* __restrict__ bias,
                     const float* __restrict__ P,
                     float* __restrict__ out,
                     unsigned* __restrict__ grpCnt,   // 32 x 128B lines
                     unsigned* __restrict__ grpDone,  // 32 x 128B lines
                     unsigned* __restrict__ consDone, // 32 x 128B lines
                     unsigned* __restrict__ flagB,    // 32 x 128B lines
                     float* __restrict__ hbuf,            // [32][512] f32
                     unsigned short* __restrict__ hpreH,  // [32][4096] fp16 hi
                     unsigned short* __restrict__ hpreL,  // [32][4096] fp16 lo
                     unsigned short* __restrict__ PB)     // consumer P-frags
{
  __shared__ __align__(16) char smem[100352 + 16384];
  _Float16* xh_hi = (_Float16*)smem;                        // 32*520 halves
  _Float16* xh_lo = xh_hi + B_ * PITC;
  float (*zb)[64][33] = (float (*)[64][33])(smem + 66560);  // [4][64][33]
  float* red = (float*)(smem + 100352);                     // [8][32][16]
  __shared__ float cst[512];
  __shared__ float biasL[64];

  const int tid  = threadIdx.x;
  const int blk  = blockIdx.x;
  const int lane = tid & 63;
  const int w    = tid >> 6;   // wave 0..7
  const int ch   = w & 1;      // phase A col-half
  const int sq   = w >> 1;     // phase A k-quarter
  const int g    = blk >> 3;   // barrier group

  // ---- one-time setup -------------------------------------------------
  if (tid < 64) {
    int gg = tid >> 4, j = tid & 15;
    biasL[tid] = bias[gg * U_ + blk * 16 + j];
  }
  cst[tid] = 0.f;

  // Phase A weight B-fragments (split fp16) into registers.
  half8 bhi[2][2][4], blo[2][2][4];
  {
    const int n = lane & 15, q = lane >> 4;
#pragma unroll
    for (int c = 0; c < 2; ++c) {
      const float* Wsrc = c ? R : Wk;
#pragma unroll
      for (int nt = 0; nt < 2; ++nt) {
        int cib  = ch * 32 + nt * 16 + n;
        int gcol = (cib >> 4) * U_ + blk * 16 + (cib & 15);
#pragma unroll
        for (int u = 0; u < 4; ++u) {
          half8 th, tl;
#pragma unroll
          for (int i = 0; i < 8; ++i) {
            int k = (sq * 4 + u) * 32 + q * 8 + i;
            _Float16 hi, lo;
            split_h(Wsrc[(size_t)k * G4 + gcol], hi, lo);
            th[i] = hi; tl[i] = lo;
          }
          bhi[nt][c][u] = th;
          blo[nt][c][u] = tl;
        }
      }
    }
  }

  // Consumer P-fragments (split fp16) -> per-block ws region, self-read later
  // (same-CU caches; normal stores+loads, syncthreads orders them).
  // entry e = ((w*16+kc)*4+q)*16+n, 32B each (half8 hi + half8 lo).
  unsigned short* myPB = PB + (size_t)blk * 131072;   // 8192 entries * 16 halves
  if (blk < NCONS) {
    for (int e = tid; e < 8192; e += NTHR) {
      int n = e & 15, q = (e >> 4) & 3, kc = (e >> 6) & 15, ww = e >> 10;
      int col = blk * CPBC + n;
      half8 th, tl;
#pragma unroll
      for (int j = 0; j < 8; ++j) {
        int k = ww * 512 + kc * 32 + q * 8 + j;
        _Float16 hi, lo;
        split_h(P[(size_t)k * PJ + col], hi, lo);
        th[j] = hi; tl[j] = lo;
      }
      *(half8*)(myPB + (size_t)e * 16)     = th;
      *(half8*)(myPB + (size_t)e * 16 + 8) = tl;
    }
  }
  __syncthreads();

  // ---- time loop ------------------------------------------------------
  for (int t = 0; t < S_; ++t) {
    const unsigned ep = (unsigned)t + 1u;
    floatx4 acc00 = {0.f, 0.f, 0.f, 0.f};
    floatx4 acc01 = acc00, acc10 = acc00, acc11 = acc00;
    floatx4 accL00 = acc00, accL01 = acc00, accL10 = acc00, accL11 = acc00;
    const int m_ = lane & 15, q = lane >> 4;

    // ===== chunk 0: x_t (independent of h) — runs BEFORE the h wait =====
#pragma unroll
    for (int it = 0; it < 4; ++it) {
      int c8 = tid + it * NTHR;
      int b  = c8 >> 6;
      int kg = (c8 & 63) << 3;
      const float* src = x + (size_t)(b * S_ + t) * D_ + kg;   // normal: cached
      float4 f0 = *(const float4*)src;
      float4 f1 = *(const float4*)(src + 4);
      half8 th, tl; _Float16 hi, lo;
      split_h(f0.x, hi, lo); th[0] = hi; tl[0] = lo;
      split_h(f0.y, hi, lo); th[1] = hi; tl[1] = lo;
      split_h(f0.z, hi, lo); th[2] = hi; tl[2] = lo;
      split_h(f0.w, hi, lo); th[3] = hi; tl[3] = lo;
      split_h(f1.x, hi, lo); th[4] = hi; tl[4] = lo;
      split_h(f1.y, hi, lo); th[5] = hi; tl[5] = lo;
      split_h(f1.z, hi, lo); th[6] = hi; tl[6] = lo;
      split_h(f1.w, hi, lo); th[7] = hi; tl[7] = lo;
      *(half8*)(xh_hi + b * PITC + kg) = th;
      *(half8*)(xh_lo + b * PITC + kg) = tl;
    }
    __syncthreads();
#pragma unroll
    for (int u = 0; u < 4; ++u) {
      int ko = (sq * 4 + u) * 32 + q * 8;
      half8 ah0 = *(const half8*)(xh_hi + m_ * PITC + ko);
      half8 ah1 = *(const half8*)(xh_hi + (16 + m_) * PITC + ko);
      half8 al0 = *(const half8*)(xh_lo + m_ * PITC + ko);
      half8 al1 = *(const half8*)(xh_lo + (16 + m_) * PITC + ko);
      acc00 = __builtin_amdgcn_mfma_f32_16x16x32_f16(ah0, bhi[0][0][u], acc00, 0, 0, 0);
      acc01 = __builtin_amdgcn_mfma_f32_16x16x32_f16(ah0, bhi[1][0][u], acc01, 0, 0, 0);
      acc10 = __builtin_amdgcn_mfma_f32_16x16x32_f16(ah1, bhi[0][0][u], acc10, 0, 0, 0);
      acc11 = __builtin_amdgcn_mfma_f32_16x16x32_f16(ah1, bhi[1][0][u], acc11, 0, 0, 0);
      accL00 = __builtin_amdgcn_mfma_f32_16x16x32_f16(ah0, blo[0][0][u], accL00, 0, 0, 0);
      accL01 = __builtin_amdgcn_mfma_f32_16x16x32_f16(ah0, blo[1][0][u], accL01, 0, 0, 0);
      accL10 = __builtin_amdgcn_mfma_f32_16x16x32_f16(ah1, blo[0][0][u], accL10, 0, 0, 0);
      accL11 = __builtin_amdgcn_mfma_f32_16x16x32_f16(ah1, blo[1][0][u], accL11, 0, 0, 0);
      accL00 = __builtin_amdgcn_mfma_f32_16x16x32_f16(al0, bhi[0][0][u], accL00, 0, 0, 0);
      accL01 = __builtin_amdgcn_mfma_f32_16x16x32_f16(al0, bhi[1][0][u], accL01, 0, 0, 0);
      accL10 = __builtin_amdgcn_mfma_f32_16x16x32_f16(al1, bhi[0][0][u], accL10, 0, 0, 0);
      accL11 = __builtin_amdgcn_mfma_f32_16x16x32_f16(al1, bhi[1][0][u], accL11, 0, 0, 0);
    }
    __syncthreads();

    // ===== wait for h(t-1) (flagB >= t), then chunk 1: h =====
    if (tid == 0 && t > 0) {
      while (ldg_dev_u32(&flagB[g * 32]) < (unsigned)t)
        __builtin_amdgcn_s_sleep(2);
    }
    __syncthreads();
#pragma unroll
    for (int it = 0; it < 4; ++it) {
      int c8 = tid + it * NTHR;
      int b  = c8 >> 6;
      int kg = (c8 & 63) << 3;
      const float* src = hbuf + b * PJ + kg;     // sc1: LLC-coherent
      float2 g0 = ldg_dev8(src);
      float2 g1 = ldg_dev8(src + 2);
      float2 g2 = ldg_dev8(src + 4);
      float2 g3 = ldg_dev8(src + 6);
      float f[8] = {g0.x, g0.y, g1.x, g1.y, g2.x, g2.y, g3.x, g3.y};
      half8 th, tl;
#pragma unroll
      for (int i = 0; i < 8; ++i) {
        _Float16 hi, lo;
        split_h(f[i], hi, lo);
        th[i] = hi; tl[i] = lo;
      }
      *(half8*)(xh_hi + b * PITC + kg) = th;
      *(half8*)(xh_lo + b * PITC + kg) = tl;
    }
    __syncthreads();
#pragma unroll
    for (int u = 0; u < 4; ++u) {
      int ko = (sq * 4 + u) * 32 + q * 8;
      half8 ah0 = *(const half8*)(xh_hi + m_ * PITC + ko);
      half8 ah1 = *(const half8*)(xh_hi + (16 + m_) * PITC + ko);
      half8 al0 = *(const half8*)(xh_lo + m_ * PITC + ko);
      half8 al1 = *(const half8*)(xh_lo + (16 + m_) * PITC + ko);
      acc00 = __builtin_amdgcn_mfma_f32_16x16x32_f16(ah0, bhi[0][1][u], acc00, 0, 0, 0);
      acc01 = __builtin_amdgcn_mfma_f32_16x16x32_f16(ah0, bhi[1][1][u], acc01, 0, 0, 0);
      acc10 = __builtin_amdgcn_mfma_f32_16x16x32_f16(ah1, bhi[0][1][u], acc10, 0, 0, 0);
      acc11 = __builtin_amdgcn_mfma_f32_16x16x32_f16(ah1, bhi[1][1][u], acc11, 0, 0, 0);
      accL00 = __builtin_amdgcn_mfma_f32_16x16x32_f16(ah0, blo[0][1][u], accL00, 0, 0, 0);
      accL01 = __builtin_amdgcn_mfma_f32_16x16x32_f16(ah0, blo[1][1][u], accL01, 0, 0, 0);
      accL10 = __builtin_amdgcn_mfma_f32_16x16x32_f16(ah1, blo[0][1][u], accL10, 0, 0, 0);
      accL11 = __builtin_amdgcn_mfma_f32_16x16x32_f16(ah1, blo[1][1][u], accL11, 0, 0, 0);
      accL00 = __builtin_amdgcn_mfma_f32_16x16x32_f16(al0, bhi[0][1][u], accL00, 0, 0, 0);
      accL01 = __builtin_amdgcn_mfma_f32_16x16x32_f16(al0, bhi[1][1][u], accL01, 0, 0, 0);
      accL10 = __builtin_amdgcn_mfma_f32_16x16x32_f16(al1, bhi[0][1][u], accL10, 0, 0, 0);
      accL11 = __builtin_amdgcn_mfma_f32_16x16x32_f16(al1, bhi[1][1][u], accL11, 0, 0, 0);
    }
    __syncthreads();

    // D-frag -> zb[sq][col][batch]
    {
      int n  = lane & 15;
      int c0 = ch * 32 + n, c1 = ch * 32 + 16 + n;
      int r0 = q * 4,       r1 = 16 + q * 4;
#pragma unroll
      for (int i = 0; i < 4; ++i) {
        zb[sq][c0][r0 + i] = acc00[i] + accL00[i] * LINV;
        zb[sq][c1][r0 + i] = acc01[i] + accL01[i] * LINV;
        zb[sq][c0][r1 + i] = acc10[i] + accL10[i] * LINV;
        zb[sq][c1][r1 + i] = acc11[i] + accL11[i] * LINV;
      }
    }
    __syncthreads();

    // gates + cell update; hpre -> split-fp16 planes (paired u32 sc1 stores)
    {
      int p = tid;                      // 0..511
      int b = p >> 4, j = p & 15;
      float zi = zb[0][j][b] + zb[1][j][b] + zb[2][j][b] + zb[3][j][b] + biasL[j];
      float zf = zb[0][16+j][b] + zb[1][16+j][b] + zb[2][16+j][b] + zb[3][16+j][b] + biasL[16+j];
      float zc = zb[0][32+j][b] + zb[1][32+j][b] + zb[2][32+j][b] + zb[3][32+j][b] + biasL[32+j];
      float zo = zb[0][48+j][b] + zb[1][48+j][b] + zb[2][48+j][b] + zb[3][48+j][b] + biasL[48+j];
      float ig = fminf(fmaxf(0.2f * zi + 0.5f, 0.f), 1.f);
      float fg = fminf(fmaxf(0.2f * zf + 0.5f, 0.f), 1.f);
      float og = fminf(fmaxf(0.2f * zo + 0.5f, 0.f), 1.f);
      float cn = fg * cst[p] + ig * tanhf(zc);
      float hp = og * tanhf(cn);                 // uses UNCLIPPED c
      cst[p] = fminf(fmaxf(cn, -3.f), 3.f);      // cell clip

      _Float16 hh, hl;
      split_h(hp, hh, hl);
      unsigned both = (unsigned)__builtin_bit_cast(unsigned short, hh) |
                      ((unsigned)__builtin_bit_cast(unsigned short, hl) << 16);
      unsigned nb = __shfl_xor(both, 1, 64);
      if ((j & 1) == 0) {
        unsigned idx2 = (unsigned)(b * U_ + blk * 16 + j) >> 1;
        stg_dev_u32((unsigned*)hpreH + idx2, (both & 0xffffu) | (nb << 16));
        stg_dev_u32((unsigned*)hpreL + idx2, (both >> 16) | (nb & 0xffff0000u));
      }
    }
    __syncthreads();   // drains hpre sc1 stores (vmcnt 0) before arrival

    // arrival: group counter; leader publishes grpDone[g] = ep
    if (tid == 0) {
      unsigned old = __hip_atomic_fetch_add(&grpCnt[g * 32], 1u,
                         __ATOMIC_RELAXED, __HIP_MEMORY_SCOPE_AGENT);
      if (old == ep * 8u - 1u)
        stg_dev_u32(&grpDone[g * 32], ep);
    }
    // producers loop straight to next step's x-chunk (overlaps phase B)

    // ===== phase B (32 consumer blocks) =====
    if (blk < NCONS) {
      if (w == 0) {          // lane-parallel wait for all 32 groups
        for (;;) {
          unsigned v = (lane < 32) ? ldg_dev_u32(&grpDone[lane * 32]) : ep;
          if (__all((int)(v >= ep))) break;
          __builtin_amdgcn_s_sleep(2);
        }
      }
      __syncthreads();

      floatx4 pa0 = {0.f, 0.f, 0.f, 0.f};
      floatx4 pa1 = pa0, pL0 = pa0, pL1 = pa0;
      const unsigned short* rowH0 = hpreH + m_ * U_ + w * 512;
      const unsigned short* rowH1 = hpreH + (16 + m_) * U_ + w * 512;
      const unsigned short* rowL0 = hpreL + m_ * U_ + w * 512;
      const unsigned short* rowL1 = hpreL + (16 + m_) * U_ + w * 512;
      const unsigned short* pbp = myPB + (w * 64 + q) * 256 + (lane & 15) * 16;
#pragma unroll
      for (int kc = 0; kc < 16; ++kc) {
        int ko = kc * 32 + q * 8;
        half8 ah0 = ld16_dev(rowH0 + ko);
        half8 ah1 = ld16_dev(rowH1 + ko);
        half8 al0 = ld16_dev(rowL0 + ko);
        half8 al1 = ld16_dev(rowL1 + ko);
        half8 ph  = *(const half8*)(pbp + kc * 1024);      // normal: L2-hot
        half8 pl  = *(const half8*)(pbp + kc * 1024 + 8);
        pa0 = __builtin_amdgcn_mfma_f32_16x16x32_f16(ah0, ph, pa0, 0, 0, 0);
        pa1 = __builtin_amdgcn_mfma_f32_16x16x32_f16(ah1, ph, pa1, 0, 0, 0);
        pL0 = __builtin_amdgcn_mfma_f32_16x16x32_f16(ah0, pl, pL0, 0, 0, 0);
        pL1 = __builtin_amdgcn_mfma_f32_16x16x32_f16(ah1, pl, pL1, 0, 0, 0);
        pL0 = __builtin_amdgcn_mfma_f32_16x16x32_f16(al0, ph, pL0, 0, 0, 0);
        pL1 = __builtin_amdgcn_mfma_f32_16x16x32_f16(al1, ph, pL1, 0, 0, 0);
      }
      int n = lane & 15;
#pragma unroll
      for (int i = 0; i < 4; ++i) {
        red[(w * 32 + q * 4 + i) * 16 + n]      = pa0[i] + pL0[i] * LINV;
        red[(w * 32 + 16 + q * 4 + i) * 16 + n] = pa1[i] + pL1[i] * LINV;
      }
      __syncthreads();
      {
        int m = tid >> 4, col = tid & 15;
        float s = 0.f;
#pragma unroll
        for (int ww = 0; ww < 8; ++ww)
          s += red[(ww * 32 + m) * 16 + col];
        float h = fminf(fmaxf(s, -3.f), 3.f);
        int colg = blk * CPBC + col;
        stg_dev(out + (size_t)(m * S_ + t) * PJ + colg, h);
        stg_dev(hbuf + m * PJ + colg, h);
      }
      __syncthreads();   // drain out/hbuf sc1 stores
      if (tid == 0)
        stg_dev_u32(&consDone[blk * 32], ep);
      if (blk == 0 && w == 0) {   // aggregate + fan out h-ready flag
        for (;;) {
          unsigned v = (lane < 32) ? ldg_dev_u32(&consDone[lane * 32]) : ep;
          if (__all((int)(v >= ep))) break;
          __builtin_amdgcn_s_sleep(2);
        }
        if (lane < 32)
          stg_dev_u32(&flagB[lane * 32], ep);
      }
    }
  }
}

extern "C" void kernel_launch(void* const* d_in, const int* in_sizes, int n_in,
                              void* d_out, int out_size, void* d_ws, size_t ws_size,
                              hipStream_t stream) {
  const float* x_   = (const float*)d_in[0];
  const float* Wk   = (const float*)d_in[1];
  const float* R_   = (const float*)d_in[2];
  const float* bias = (const float*)d_in[3];
  const float* P_   = (const float*)d_in[4];
  float* out = (float*)d_out;

  unsigned char* ws = (unsigned char*)d_ws;
  unsigned* grpCnt   = (unsigned*)ws;                 // 4 KB (32 lines)
  unsigned* grpDone  = (unsigned*)(ws + 4096);        // 4 KB
  unsigned* consDone = (unsigned*)(ws + 8192);        // 4 KB
  unsigned* flagB    = (unsigned*)(ws + 12288);       // 4 KB
  float* hbuf        = (float*)(ws + 16384);          // 64 KB
  unsigned short* hpreH = (unsigned short*)(ws + 16384 + 65536);           // 256 KB
  unsigned short* hpreL = (unsigned short*)(ws + 16384 + 65536 + 262144);  // 256 KB
  unsigned short* PB    = (unsigned short*)(ws + 16384 + 65536 + 524288);  // 8 MB

  // zero flags + initial h every launch
  (void)hipMemsetAsync(d_ws, 0, 16384 + 65536, stream);

  lstm_persistent<<<dim3(NBLK), dim3(NTHR), 0, stream>>>(
      x_, Wk, R_, bias, P_, out, grpCnt, grpDone, consDone, flagB,
      hbuf, hpreH, hpreL, PB);
}